// Round 7
// baseline (228.039 us; speedup 1.0000x reference)
//
#include <hip/hip_runtime.h>

#define NN   4096
#define NQ   (NN*4)
#define QQ   4
#define LTT  8
#define DD   32
#define MM   128
#define SIG2 0.001f
#define JIT  1e-5f
#define LOG2E 1.4426950408889634f

typedef _Float16 half8 __attribute__((ext_vector_type(8)));
typedef float    f32x4 __attribute__((ext_vector_type(4)));

__device__ __forceinline__ float fexp2(float x) { return exp2f(x); }

__device__ __forceinline__ float rlane(float v, int l) {
    return __uint_as_float(__builtin_amdgcn_readlane(__float_as_uint(v), l));
}

// ============ prep (blocks 0-15) + Kuu (16-79) + sp/Zh/zeroing (80) ============
__global__ __launch_bounds__(256) void prepstatic_kernel(
    const float* __restrict__ Xm, const float* __restrict__ Xv,
    const float* __restrict__ Zg, const float* __restrict__ ls,
    const float* __restrict__ varp,
    float4* __restrict__ pk4, _Float16* __restrict__ bh,
    float* __restrict__ L1p, float* __restrict__ bbp, float* __restrict__ sumsP,
    float* __restrict__ Kuu, float* __restrict__ sp, _Float16* __restrict__ Zh,
    float* __restrict__ Yg, float* __restrict__ scalars, int* __restrict__ cnt)
{
    int b = blockIdx.x, tid = threadIdx.x;
    if (b < 16) {
        __shared__ float ra[256], rb[256], rc[256];
        int n = b*256 + tid;
        float var = varp[0];
        float slog2 = 0.f, slog1 = 0.f, T1 = 0.f, c0 = 0.f;
        #pragma unroll 8
        for (int q = 0; q < DD; ++q) {
            float xm = Xm[n*QQ + q];
            float xv = Xv[n*QQ + q];
            float l  = ls[q];
            float l2 = l*l;
            float a    = 1.0f / (2.0f*xv + l2);
            float dinv = 1.0f / (l2 + xv);
            float4 v;
            v.x = LOG2E * a * xm;
            v.y = LOG2E * (-0.25f * a);
            v.z = dinv;
            v.w = -2.0f * dinv * xm;
            pk4[n*DD + q] = v;
            bh[n*DD + q] = (_Float16)(0.5f * LOG2E * (1.0f/l2 - a));
            slog2 += log1pf(2.0f*xv/l2);
            slog1 += log1pf(xv/l2);
            T1    += a*xm*xm;
            c0    += dinv*xm*xm;
        }
        L1p[n] = 0.5f * LOG2E * (2.0f*logf(var) - 0.5f*slog2 - T1);
        bbp[n] = logf(var) - 0.5f*slog1 - 0.5f*c0;
        float s1 = 0.f, s2 = 0.f, s3 = 0.f;
        #pragma unroll
        for (int c = 0; c < QQ; ++c) {
            float mo = Xm[(n+LTT)*QQ + c];
            float vo = Xv[(n+LTT)*QQ + c];
            s1 += vo + mo*mo;
            s2 += logf(vo);
        }
        if (n < LTT) {
            #pragma unroll
            for (int c = 0; c < QQ; ++c) {
                float mb = Xm[n*QQ+c], vb = Xv[n*QQ+c];
                s3 += mb*mb + vb;
            }
        }
        ra[tid]=s1; rb[tid]=s2; rc[tid]=s3;
        __syncthreads();
        for (int s = 128; s; s >>= 1) {
            if (tid < s) { ra[tid]+=ra[tid+s]; rb[tid]+=rb[tid+s]; rc[tid]+=rc[tid+s]; }
            __syncthreads();
        }
        if (tid == 0) { sumsP[b*3+0]=ra[0]; sumsP[b*3+1]=rb[0]; sumsP[b*3+2]=rc[0]; }
    } else if (b < 80) {
        int idx = (b-16)*256 + tid;
        int i = idx >> 7, j = idx & 127;
        float var = varp[0];
        float s = 0.f;
        for (int q = 0; q < DD; ++q) {
            float l = ls[q];
            float d = (Zg[i*DD+q] - Zg[j*DD+q]) / l;
            s += d*d;
        }
        float v = var * __expf(-0.5f*s);
        if (i == j) v += JIT;
        Kuu[idx] = v;
    } else {
        if (tid < MM) {
            float s = 0.f;
            for (int q = 0; q < DD; ++q) {
                float l = ls[q]; float z = Zg[tid*DD+q];
                s += z*z / (4.0f*l*l);
            }
            sp[tid] = LOG2E * s;
        }
        for (int e = tid; e < MM*DD; e += 256) Zh[e] = (_Float16)Zg[e];
        for (int e = tid; e < 512; e += 256) Yg[e] = 0.f;
        if (tid < 8) scalars[tid] = 0.f;
        if (tid == 0) *cnt = 0;
    }
}

// ============ linalg device functions, 256 threads, LDS stride 132 ============
__device__ __forceinline__ void dev_chol(float* mat, int tid)
{
    int wv = tid >> 6, ln = tid & 63;
    for (int p = 0; p < 8; ++p) {
        int base = p*16;
        if (wv == 0) {
            int r0 = base + ln, r1 = r0 + 64;
            bool h0 = r0 < 128, h1 = r1 < 128;
            float a0[16], a1[16];
            #pragma unroll
            for (int c = 0; c < 16; ++c) {
                a0[c] = h0 ? mat[r0*132 + base + c] : 0.f;
                a1[c] = h1 ? mat[r1*132 + base + c] : 0.f;
            }
            #pragma unroll
            for (int kk = 0; kk < 16; ++kk) {
                float d   = rlane(a0[kk], kk);
                float rdk = rsqrtf(d);
                float sq  = d * rdk;
                a0[kk] = (ln == kk) ? sq : a0[kk] * rdk;
                a1[kk] *= rdk;
                #pragma unroll
                for (int j = kk+1; j < 16; ++j) {
                    float ljv = rlane(a0[kk], j);
                    a0[j] = fmaf(-a0[kk], ljv, a0[j]);
                    a1[j] = fmaf(-a1[kk], ljv, a1[j]);
                }
            }
            #pragma unroll
            for (int c = 0; c < 16; ++c) {
                if (h0) mat[r0*132 + base + c] = a0[c];
                if (h1) mat[r1*132 + base + c] = a1[c];
            }
        }
        __syncthreads();
        int S = 112 - base;
        if (S > 0) {
            int T = S >> 2, nb = base + 16;
            int nT = (T*(T+1)) >> 1;
            for (int t = tid; t < nT; t += 256) {
                int ti = (int)(0.5f*(sqrtf(8.f*(float)t + 1.f) - 1.f));
                if ((ti+1)*(ti+2)/2 <= t) ++ti;
                else if (ti*(ti+1)/2 > t) --ti;
                int tj = t - ((ti*(ti+1))>>1);
                int i0 = nb + ti*4, j0 = nb + tj*4;
                float ac[4][4];
                #pragma unroll
                for (int r = 0; r < 4; ++r)
                    #pragma unroll
                    for (int s = 0; s < 4; ++s) ac[r][s] = mat[(i0+r)*132 + j0 + s];
                #pragma unroll
                for (int c4 = 0; c4 < 4; ++c4) {
                    float4 av[4], bv[4];
                    #pragma unroll
                    for (int r = 0; r < 4; ++r) {
                        av[r] = *(const float4*)&mat[(i0+r)*132 + base + c4*4];
                        bv[r] = *(const float4*)&mat[(j0+r)*132 + base + c4*4];
                    }
                    #pragma unroll
                    for (int r = 0; r < 4; ++r)
                        #pragma unroll
                        for (int s = 0; s < 4; ++s)
                            ac[r][s] -= av[r].x*bv[s].x + av[r].y*bv[s].y
                                      + av[r].z*bv[s].z + av[r].w*bv[s].w;
                }
                #pragma unroll
                for (int r = 0; r < 4; ++r)
                    #pragma unroll
                    for (int s = 0; s < 4; ++s) mat[(i0+r)*132 + j0 + s] = ac[r][s];
            }
        }
        __syncthreads();
    }
}

__device__ __forceinline__ void dev_dinv(const float* mat, float* dinvb, int tid)
{
    int wv = tid >> 6, ln = tid & 63;
    if (ln < 16) {
        int c = ln;
        for (int bd = wv; bd < 8; bd += 4) {
            int base = bd*16;
            float x[16];
            #pragma unroll
            for (int i = 0; i < 16; ++i) {
                float dii = mat[(base+i)*132 + base + i];
                float s = 0.f;
                #pragma unroll
                for (int j = 0; j < i; ++j) s += mat[(base+i)*132 + base + j] * x[j];
                float v;
                if (i < c) v = 0.f;
                else if (i == c) v = 1.0f / dii;
                else v = -s / dii;
                x[i] = v;
            }
            #pragma unroll
            for (int i = 0; i < 16; ++i) dinvb[bd*256 + i*16 + c] = x[i];
        }
    }
    __syncthreads();
}

template<int C>
__device__ __forceinline__ void dev_solve(const float* mat, const float* dinvb,
                                          float* tmp, float* rhs, int tid)
{
    const int AT = 16*C;
    int r = tid / C, cc = tid % C;
    for (int bi = 0; bi < 8; ++bi) {
        float acc = 0.f;
        if (tid < AT) {
            acc = rhs[(bi*16+r)*C + cc];
            for (int bk = 0; bk < bi; ++bk) {
                #pragma unroll
                for (int kk = 0; kk < 16; ++kk)
                    acc -= mat[(bi*16+r)*132 + bk*16+kk] * rhs[(bk*16+kk)*C + cc];
            }
        }
        __syncthreads();
        if (tid < AT) tmp[r*C + cc] = acc;
        __syncthreads();
        if (tid < AT) {
            float w = 0.f;
            #pragma unroll
            for (int kk = 0; kk < 16; ++kk)
                w += dinvb[bi*256 + r*16 + kk] * tmp[kk*C + cc];
            rhs[(bi*16+r)*C + cc] = w;
        }
        __syncthreads();
    }
}

template<int C>
__device__ __forceinline__ void dev_bsolve(const float* mat, const float* dinvb,
                                           float* tmp, float* rhs, int tid)
{
    const int AT = 16*C;
    int r = tid / C, cc = tid % C;
    for (int bi = 7; bi >= 0; --bi) {
        float acc = 0.f;
        if (tid < AT) {
            acc = rhs[(bi*16+r)*C + cc];
            for (int bj = bi+1; bj < 8; ++bj) {
                #pragma unroll
                for (int kk = 0; kk < 16; ++kk)
                    acc -= mat[(bj*16+kk)*132 + bi*16 + r] * rhs[(bj*16+kk)*C + cc];
            }
        }
        __syncthreads();
        if (tid < AT) tmp[r*C + cc] = acc;
        __syncthreads();
        if (tid < AT) {
            float w = 0.f;
            #pragma unroll
            for (int kk = 0; kk < 16; ++kk)
                w += dinvb[bi*256 + kk*16 + r] * tmp[kk*C + cc];   // Dinv^T
            rhs[(bi*16+r)*C + cc] = w;
        }
        __syncthreads();
    }
}

// ============ K2: blocks 0-127 = k1 (r, Y, psi2-zero); block 128 = chol(Kuu) ============
__global__ __launch_bounds__(256) void k1chol_kernel(
    const float* __restrict__ Xm, const float* __restrict__ Zg,
    const float4* __restrict__ pk4, const float* __restrict__ L1p,
    const float* __restrict__ bbp, const float* __restrict__ sp,
    float* __restrict__ r_g, float* __restrict__ Yg, float* __restrict__ psi2,
    const float* __restrict__ Kuu, float* __restrict__ Lg,
    float* __restrict__ Dinvg, float* __restrict__ scalars)
{
    __shared__ float shm[19200];   // 76.8 KB union
    int tid = threadIdx.x;
    if (blockIdx.x < 128) {
        float* Zl    = shm;            // 128*33 = 4224
        float* yredl = shm + 4224;     // 512
        { int e = blockIdx.x*128 + tid; if (tid < 128) psi2[e] = 0.f; }
        for (int e = tid; e < MM*DD; e += 256)
            Zl[(e>>5)*33 + (e&31)] = Zg[e];
        __syncthreads();
        int m = tid & 127, half = tid >> 7;
        float zr[DD];
        #pragma unroll
        for (int q = 0; q < DD; ++q) zr[q] = Zl[m*33 + q];
        float sm = sp[m];
        float y0=0.f, y1=0.f, y2=0.f, y3=0.f;
        int n0 = blockIdx.x*32 + half*16;
        for (int i = 0; i < 16; ++i) {
            int n = n0 + i;
            float L1n = L1p[n], bbn = bbp[n];
            const float4* pkn = pk4 + n*DD;
            float racc = 0.f, q1 = 0.f;
            #pragma unroll
            for (int q = 0; q < DD; ++q) {
                float4 v = pkn[q];
                float z = zr[q];
                racc = fmaf(v.x, z, racc);
                racc = fmaf(v.y, z*z, racc);
                float t = fmaf(v.z, z, v.w);
                q1 = fmaf(t, z, q1);
            }
            r_g[n*MM + m] = L1n + racc - sm;
            float p1 = __expf(fmaf(-0.5f, q1, bbn));
            float4 xo = *(const float4*)(Xm + (LTT+n)*QQ);
            y0 = fmaf(p1, xo.x, y0); y1 = fmaf(p1, xo.y, y1);
            y2 = fmaf(p1, xo.z, y2); y3 = fmaf(p1, xo.w, y3);
        }
        if (half == 0) {
            yredl[m*4+0]=y0; yredl[m*4+1]=y1; yredl[m*4+2]=y2; yredl[m*4+3]=y3;
        }
        __syncthreads();
        if (half == 1) {
            yredl[m*4+0]+=y0; yredl[m*4+1]+=y1; yredl[m*4+2]+=y2; yredl[m*4+3]+=y3;
        }
        __syncthreads();
        for (int e = tid; e < 512; e += 256) atomicAdd(&Yg[e], yredl[e]);
    } else {
        float* mat   = shm;            // 16896
        float* dinvb = shm + 16896;    // 2048
        float* red   = shm + 18944;    // 256
        for (int e = tid; e < 16384; e += 256) mat[(e>>7)*132 + (e&127)] = Kuu[e];
        __syncthreads();
        dev_chol(mat, tid);
        float ld = (tid < 128) ? logf(mat[tid*132 + tid]) : 0.f;
        red[tid] = ld; __syncthreads();
        for (int s = 128; s; s >>= 1) { if (tid < s) red[tid] += red[tid+s]; __syncthreads(); }
        if (tid == 0) scalars[0] = red[0];
        dev_dinv(mat, dinvb, tid);
        for (int e = tid; e < 16384; e += 256) Lg[e] = mat[(e>>7)*132 + (e&127)];
        for (int e = tid; e < 2048; e += 256) Dinvg[e] = dinvb[e];
    }
}

// ============ K3: psi2 pure — symmetric tiles, direct global reads, 4KB LDS ============
__global__ __launch_bounds__(256) void psi2_kernel(
    const _Float16* __restrict__ Zh, const float* __restrict__ r_g,
    const _Float16* __restrict__ bh, float* __restrict__ psi2)
{
    __shared__ float pacc[4][64][4];
    int tid = threadIdx.x;
    int w = tid >> 6, l = tid & 63, lm = l & 15, lg = l >> 4;
    int b = blockIdx.x;
    int nq = b / 36, t = b - nq*36;
    int kt = (int)(0.5f*(sqrtf(8.f*(float)t + 1.f) - 1.f));
    if ((kt+1)*(kt+2)/2 <= t) ++kt;
    else if (kt*(kt+1)/2 > t) --kt;
    int mt = t - ((kt*(kt+1))>>1);     // mt <= kt

    half8 Bf = ((const half8*)Zh)[(kt*16 + lm)*4 + lg];
    half8 Zm = ((const half8*)Zh)[(mt*16 + lm)*4 + lg];
    f32x4 z4; z4[0]=0.f; z4[1]=0.f; z4[2]=0.f; z4[3]=0.f;
    f32x4 acc = z4;
    int n0g = nq*512 + w*128;
    const float* rbase = r_g + (size_t)n0g*MM;
    const half8* bbase = (const half8*)bh + (size_t)n0g*4;
    #pragma unroll 4
    for (int i = 0; i < 128; ++i) {
        half8 bf = bbase[i*4 + lg];
        half8 A = Zm * bf;
        const float* rn = rbase + i*MM;
        f32x4 rm = *(const f32x4*)(rn + mt*16 + lg*4);
        float rk = rn[kt*16 + lm];
        f32x4 p = __builtin_amdgcn_mfma_f32_16x16x32_f16(A, Bf, z4, 0, 0, 0);
        acc[0] += fexp2(p[0] + rm[0] + rk);
        acc[1] += fexp2(p[1] + rm[1] + rk);
        acc[2] += fexp2(p[2] + rm[2] + rk);
        acc[3] += fexp2(p[3] + rm[3] + rk);
    }
    #pragma unroll
    for (int j = 0; j < 4; ++j) pacc[w][l][j] = acc[j];
    __syncthreads();
    {
        int ll = tid >> 2, j = tid & 3;
        float s = pacc[0][ll][j] + pacc[1][ll][j] + pacc[2][ll][j] + pacc[3][ll][j];
        int row = mt*16 + (ll >> 4)*4 + j;
        int col = kt*16 + (ll & 15);
        atomicAdd(&psi2[row*MM + col], s);
        if (mt != kt) atomicAdd(&psi2[col*MM + row], s);
    }
}

// ============ K4: block0 = chol(G)+Y-solve; blocks 1-16 = trace; elect final ============
__global__ __launch_bounds__(256) void cholG_kernel(
    const float* __restrict__ Kuu, const float* __restrict__ psi2,
    const float* __restrict__ Yg, const float* __restrict__ Lg,
    const float* __restrict__ Dinvg, const float* __restrict__ varp,
    const float* __restrict__ sumsP,
    float* __restrict__ scalars, int* __restrict__ cnt, float* __restrict__ out)
{
    __shared__ float mat[128*132];
    __shared__ float dinvb[8*256];
    __shared__ float rhs[128*8];
    __shared__ float tmp[128];
    __shared__ float red[256];
    int tid = threadIdx.x;
    if (blockIdx.x == 0) {
        for (int e = tid; e < 16384; e += 256)
            mat[(e>>7)*132 + (e&127)] = Kuu[e] + (1.0f/SIG2)*psi2[e];
        __syncthreads();
        dev_chol(mat, tid);
        float ld = (tid < 128) ? logf(mat[tid*132 + tid]) : 0.f;
        red[tid] = ld; __syncthreads();
        for (int s = 128; s; s >>= 1) { if (tid < s) red[tid] += red[tid+s]; __syncthreads(); }
        if (tid == 0) scalars[1] = red[0];
        dev_dinv(mat, dinvb, tid);
        if (tid < 256) { rhs[tid] = Yg[tid]; rhs[tid+256] = Yg[tid+256]; }
        __syncthreads();
        dev_solve<4>(mat, dinvb, tmp, rhs, tid);
        float c2 = rhs[tid]*rhs[tid] + rhs[tid+256]*rhs[tid+256];
        red[tid] = c2; __syncthreads();
        for (int s = 128; s; s >>= 1) { if (tid < s) red[tid] += red[tid+s]; __syncthreads(); }
        if (tid == 0) scalars[2] = red[0];
    } else {
        int c0 = (blockIdx.x - 1) * 8;
        for (int e = tid; e < 16384; e += 256) mat[(e>>7)*132 + (e&127)] = Lg[e];
        for (int e = tid; e < 2048; e += 256) dinvb[e] = Dinvg[e];
        for (int e = tid; e < 1024; e += 256) {
            int i = e >> 3, cc = e & 7;
            rhs[e] = (i == c0 + cc) ? 1.0f : 0.0f;
        }
        __syncthreads();
        dev_bsolve<8>(mat, dinvb, tmp, rhs, tid);
        int i = tid & 127, cp = tid >> 7;
        float vv0=0.f, vv1=0.f, vv2=0.f, vv3=0.f;
        for (int j = 0; j < 128; ++j) {
            float pj = psi2[i*MM + j];
            vv0 = fmaf(pj, rhs[j*8 + cp*4 + 0], vv0);
            vv1 = fmaf(pj, rhs[j*8 + cp*4 + 1], vv1);
            vv2 = fmaf(pj, rhs[j*8 + cp*4 + 2], vv2);
            vv3 = fmaf(pj, rhs[j*8 + cp*4 + 3], vv3);
        }
        float part = rhs[i*8 + cp*4 + 0]*vv0 + rhs[i*8 + cp*4 + 1]*vv1
                   + rhs[i*8 + cp*4 + 2]*vv2 + rhs[i*8 + cp*4 + 3]*vv3;
        red[tid] = part; __syncthreads();
        for (int s = 128; s; s >>= 1) { if (tid < s) red[tid] += red[tid+s]; __syncthreads(); }
        if (tid == 0) atomicAdd(&scalars[3], red[0]);
    }
    if (tid == 0) {
        __threadfence();
        int old = atomicAdd(cnt, 1);
        if (old == 16) {
            float ldK  = scalars[0];
            float ldG  = atomicAdd(&scalars[1], 0.0f);
            float c2s  = atomicAdd(&scalars[2], 0.0f);
            float trr  = atomicAdd(&scalars[3], 0.0f);
            float s1=0.f, s2=0.f, s3=0.f;
            for (int b2 = 0; b2 < 16; ++b2) {
                s1 += sumsP[b2*3+0]; s2 += sumsP[b2*3+1]; s3 += sumsP[b2*3+2];
            }
            float var = varp[0];
            float trAAT   = trr / SIG2;
            float logdetB = 2.0f * (ldG - ldK);
            float sumc2   = c2s / (SIG2*SIG2);
            float psi0    = (float)NN * var;
            const float LOG2PI = 1.837877066409345f;
            float NQf = (float)NQ;
            float bound = -0.5f*NQf*(LOG2PI + logf(SIG2));
            bound += -0.5f/SIG2 * s1;
            bound += -0.5f*(float)QQ*(psi0/SIG2 - trAAT);
            bound += -0.5f*(float)QQ*logdetB;
            bound += 0.5f*sumc2;
            bound += 0.5f*s2 + 0.5f*NQf*LOG2PI;
            bound += -(float)(LTT*QQ)*LOG2PI - 0.5f*s3;
            out[0] = bound;
        }
    }
}

extern "C" void kernel_launch(void* const* d_in, const int* in_sizes, int n_in,
                              void* d_out, int out_size, void* d_ws, size_t ws_size,
                              hipStream_t stream)
{
    (void)in_sizes; (void)n_in; (void)out_size; (void)ws_size;
    const float* Xm   = (const float*)d_in[0];
    const float* Xv   = (const float*)d_in[1];
    const float* Zg   = (const float*)d_in[2];
    const float* ls   = (const float*)d_in[3];
    const float* varp = (const float*)d_in[4];

    float* p = (float*)d_ws;
    float4*   pk4   = (float4*)p;       p += NN*DD*4;
    float*    r_g   = p;                p += NN*MM;
    _Float16* bh    = (_Float16*)p;     p += NN*DD/2;
    _Float16* Zh    = (_Float16*)p;     p += MM*DD/2;
    float*    L1p   = p;                p += NN;
    float*    bbp   = p;                p += NN;
    float*    sp    = p;                p += MM;
    float*    Kuu   = p;                p += MM*MM;
    float*    Lg    = p;                p += MM*MM;
    float*    Dinvg = p;                p += 2048;
    float*    psi2  = p;                p += MM*MM;
    float*    Yg    = p;                p += 512;
    float*    sumsP = p;                p += 64;
    float*    scalars = p;              p += 8;
    int*      cnt   = (int*)p;          p += 4;

    prepstatic_kernel<<<81, 256, 0, stream>>>(Xm, Xv, Zg, ls, varp,
                                              pk4, bh, L1p, bbp, sumsP, Kuu, sp, Zh,
                                              Yg, scalars, cnt);
    k1chol_kernel<<<129, 256, 0, stream>>>(Xm, Zg, pk4, L1p, bbp, sp, r_g, Yg, psi2,
                                           Kuu, Lg, Dinvg, scalars);
    psi2_kernel<<<288, 256, 0, stream>>>(Zh, r_g, bh, psi2);
    cholG_kernel<<<17, 256, 0, stream>>>(Kuu, psi2, Yg, Lg, Dinvg, varp, sumsP,
                                         scalars, cnt, (float*)d_out);
}

// Round 8
// 187.551 us; speedup vs baseline: 1.2159x; 1.2159x over previous
//
#include <hip/hip_runtime.h>

#define NN   4096
#define NQ   (NN*4)
#define QQ   4
#define LTT  8
#define DD   32
#define MM   128
#define SIG2 0.001f
#define JIT  1e-5f
#define LOG2E 1.4426950408889634f

typedef _Float16 half8 __attribute__((ext_vector_type(8)));
typedef float    f32x4 __attribute__((ext_vector_type(4)));

__device__ __forceinline__ float fexp2(float x) { return exp2f(x); }

__device__ __forceinline__ float rlane(float v, int l) {
    return __uint_as_float(__builtin_amdgcn_readlane(__float_as_uint(v), l));
}

// ============ prep (blocks 0-15) + Kuu (16-79) + sp/Zh/zeroing (80) ============
__global__ __launch_bounds__(256) void prepstatic_kernel(
    const float* __restrict__ Xm, const float* __restrict__ Xv,
    const float* __restrict__ Zg, const float* __restrict__ ls,
    const float* __restrict__ varp,
    float4* __restrict__ pk4, _Float16* __restrict__ bh,
    float* __restrict__ L1p, float* __restrict__ bbp, float* __restrict__ sumsP,
    float* __restrict__ Kuu, float* __restrict__ sp, _Float16* __restrict__ Zh,
    float* __restrict__ Yg, float* __restrict__ scalars, int* __restrict__ cnt)
{
    int b = blockIdx.x, tid = threadIdx.x;
    if (b < 16) {
        __shared__ float ra[256], rb[256], rc[256];
        int n = b*256 + tid;
        float var = varp[0];
        float slog2 = 0.f, slog1 = 0.f, T1 = 0.f, c0 = 0.f;
        #pragma unroll 8
        for (int q = 0; q < DD; ++q) {
            float xm = Xm[n*QQ + q];
            float xv = Xv[n*QQ + q];
            float l  = ls[q];
            float l2 = l*l;
            float a    = 1.0f / (2.0f*xv + l2);
            float dinv = 1.0f / (l2 + xv);
            float4 v;
            v.x = LOG2E * a * xm;
            v.y = LOG2E * (-0.25f * a);
            v.z = dinv;
            v.w = -2.0f * dinv * xm;
            pk4[n*DD + q] = v;
            bh[n*DD + q] = (_Float16)(0.5f * LOG2E * (1.0f/l2 - a));
            slog2 += log1pf(2.0f*xv/l2);
            slog1 += log1pf(xv/l2);
            T1    += a*xm*xm;
            c0    += dinv*xm*xm;
        }
        L1p[n] = 0.5f * LOG2E * (2.0f*logf(var) - 0.5f*slog2 - T1);
        bbp[n] = logf(var) - 0.5f*slog1 - 0.5f*c0;
        float s1 = 0.f, s2 = 0.f, s3 = 0.f;
        #pragma unroll
        for (int c = 0; c < QQ; ++c) {
            float mo = Xm[(n+LTT)*QQ + c];
            float vo = Xv[(n+LTT)*QQ + c];
            s1 += vo + mo*mo;
            s2 += logf(vo);
        }
        if (n < LTT) {
            #pragma unroll
            for (int c = 0; c < QQ; ++c) {
                float mb = Xm[n*QQ+c], vb = Xv[n*QQ+c];
                s3 += mb*mb + vb;
            }
        }
        ra[tid]=s1; rb[tid]=s2; rc[tid]=s3;
        __syncthreads();
        for (int s = 128; s; s >>= 1) {
            if (tid < s) { ra[tid]+=ra[tid+s]; rb[tid]+=rb[tid+s]; rc[tid]+=rc[tid+s]; }
            __syncthreads();
        }
        if (tid == 0) { sumsP[b*3+0]=ra[0]; sumsP[b*3+1]=rb[0]; sumsP[b*3+2]=rc[0]; }
    } else if (b < 80) {
        int idx = (b-16)*256 + tid;
        int i = idx >> 7, j = idx & 127;
        float var = varp[0];
        float s = 0.f;
        for (int q = 0; q < DD; ++q) {
            float l = ls[q];
            float d = (Zg[i*DD+q] - Zg[j*DD+q]) / l;
            s += d*d;
        }
        float v = var * __expf(-0.5f*s);
        if (i == j) v += JIT;
        Kuu[idx] = v;
    } else {
        if (tid < MM) {
            float s = 0.f;
            for (int q = 0; q < DD; ++q) {
                float l = ls[q]; float z = Zg[tid*DD+q];
                s += z*z / (4.0f*l*l);
            }
            sp[tid] = LOG2E * s;
        }
        for (int e = tid; e < MM*DD; e += 256) Zh[e] = (_Float16)Zg[e];
        for (int e = tid; e < 512; e += 256) Yg[e] = 0.f;
        if (tid < 8) scalars[tid] = 0.f;
        if (tid == 0) *cnt = 0;
    }
}

// ============ linalg device functions, 256 threads, LDS stride 132 ============
__device__ __forceinline__ void dev_chol(float* mat, int tid)
{
    int wv = tid >> 6, ln = tid & 63;
    for (int p = 0; p < 8; ++p) {
        int base = p*16;
        if (wv == 0) {
            int r0 = base + ln, r1 = r0 + 64;
            bool h0 = r0 < 128, h1 = r1 < 128;
            float a0[16], a1[16];
            #pragma unroll
            for (int c = 0; c < 16; ++c) {
                a0[c] = h0 ? mat[r0*132 + base + c] : 0.f;
                a1[c] = h1 ? mat[r1*132 + base + c] : 0.f;
            }
            #pragma unroll
            for (int kk = 0; kk < 16; ++kk) {
                float d   = rlane(a0[kk], kk);
                float rdk = rsqrtf(d);
                float sq  = d * rdk;
                a0[kk] = (ln == kk) ? sq : a0[kk] * rdk;
                a1[kk] *= rdk;
                #pragma unroll
                for (int j = kk+1; j < 16; ++j) {
                    float ljv = rlane(a0[kk], j);
                    a0[j] = fmaf(-a0[kk], ljv, a0[j]);
                    a1[j] = fmaf(-a1[kk], ljv, a1[j]);
                }
            }
            #pragma unroll
            for (int c = 0; c < 16; ++c) {
                if (h0) mat[r0*132 + base + c] = a0[c];
                if (h1) mat[r1*132 + base + c] = a1[c];
            }
        }
        __syncthreads();
        int S = 112 - base;
        if (S > 0) {
            int T = S >> 2, nb = base + 16;
            int nT = (T*(T+1)) >> 1;
            for (int t = tid; t < nT; t += 256) {
                int ti = (int)(0.5f*(sqrtf(8.f*(float)t + 1.f) - 1.f));
                if ((ti+1)*(ti+2)/2 <= t) ++ti;
                else if (ti*(ti+1)/2 > t) --ti;
                int tj = t - ((ti*(ti+1))>>1);
                int i0 = nb + ti*4, j0 = nb + tj*4;
                float ac[4][4];
                #pragma unroll
                for (int r = 0; r < 4; ++r)
                    #pragma unroll
                    for (int s = 0; s < 4; ++s) ac[r][s] = mat[(i0+r)*132 + j0 + s];
                #pragma unroll
                for (int c4 = 0; c4 < 4; ++c4) {
                    float4 av[4], bv[4];
                    #pragma unroll
                    for (int r = 0; r < 4; ++r) {
                        av[r] = *(const float4*)&mat[(i0+r)*132 + base + c4*4];
                        bv[r] = *(const float4*)&mat[(j0+r)*132 + base + c4*4];
                    }
                    #pragma unroll
                    for (int r = 0; r < 4; ++r)
                        #pragma unroll
                        for (int s = 0; s < 4; ++s)
                            ac[r][s] -= av[r].x*bv[s].x + av[r].y*bv[s].y
                                      + av[r].z*bv[s].z + av[r].w*bv[s].w;
                }
                #pragma unroll
                for (int r = 0; r < 4; ++r)
                    #pragma unroll
                    for (int s = 0; s < 4; ++s) mat[(i0+r)*132 + j0 + s] = ac[r][s];
            }
        }
        __syncthreads();
    }
}

__device__ __forceinline__ void dev_dinv(const float* mat, float* dinvb, int tid)
{
    int wv = tid >> 6, ln = tid & 63;
    if (ln < 16) {
        int c = ln;
        for (int bd = wv; bd < 8; bd += 4) {
            int base = bd*16;
            float x[16];
            #pragma unroll
            for (int i = 0; i < 16; ++i) {
                float dii = mat[(base+i)*132 + base + i];
                float s = 0.f;
                #pragma unroll
                for (int j = 0; j < i; ++j) s += mat[(base+i)*132 + base + j] * x[j];
                float v;
                if (i < c) v = 0.f;
                else if (i == c) v = 1.0f / dii;
                else v = -s / dii;
                x[i] = v;
            }
            #pragma unroll
            for (int i = 0; i < 16; ++i) dinvb[bd*256 + i*16 + c] = x[i];
        }
    }
    __syncthreads();
}

template<int C>
__device__ __forceinline__ void dev_solve(const float* mat, const float* dinvb,
                                          float* tmp, float* rhs, int tid)
{
    const int AT = 16*C;
    int r = tid / C, cc = tid % C;
    for (int bi = 0; bi < 8; ++bi) {
        float acc = 0.f;
        if (tid < AT) {
            acc = rhs[(bi*16+r)*C + cc];
            for (int bk = 0; bk < bi; ++bk) {
                #pragma unroll
                for (int kk = 0; kk < 16; ++kk)
                    acc -= mat[(bi*16+r)*132 + bk*16+kk] * rhs[(bk*16+kk)*C + cc];
            }
        }
        __syncthreads();
        if (tid < AT) tmp[r*C + cc] = acc;
        __syncthreads();
        if (tid < AT) {
            float w = 0.f;
            #pragma unroll
            for (int kk = 0; kk < 16; ++kk)
                w += dinvb[bi*256 + r*16 + kk] * tmp[kk*C + cc];
            rhs[(bi*16+r)*C + cc] = w;
        }
        __syncthreads();
    }
}

template<int C>
__device__ __forceinline__ void dev_bsolve(const float* mat, const float* dinvb,
                                           float* tmp, float* rhs, int tid)
{
    const int AT = 16*C;
    int r = tid / C, cc = tid % C;
    for (int bi = 7; bi >= 0; --bi) {
        float acc = 0.f;
        if (tid < AT) {
            acc = rhs[(bi*16+r)*C + cc];
            for (int bj = bi+1; bj < 8; ++bj) {
                #pragma unroll
                for (int kk = 0; kk < 16; ++kk)
                    acc -= mat[(bj*16+kk)*132 + bi*16 + r] * rhs[(bj*16+kk)*C + cc];
            }
        }
        __syncthreads();
        if (tid < AT) tmp[r*C + cc] = acc;
        __syncthreads();
        if (tid < AT) {
            float w = 0.f;
            #pragma unroll
            for (int kk = 0; kk < 16; ++kk)
                w += dinvb[bi*256 + kk*16 + r] * tmp[kk*C + cc];   // Dinv^T
            rhs[(bi*16+r)*C + cc] = w;
        }
        __syncthreads();
    }
}

// ============ K2: blocks 0-255 = k1 (16 n each); block 256 = chol(Kuu) ============
__global__ __launch_bounds__(256) void k1chol_kernel(
    const float* __restrict__ Xm, const float* __restrict__ Zg,
    const float4* __restrict__ pk4, const float* __restrict__ L1p,
    const float* __restrict__ bbp, const float* __restrict__ sp,
    float* __restrict__ r_g, float* __restrict__ Yg, float* __restrict__ psi2,
    const float* __restrict__ Kuu, float* __restrict__ Lg,
    float* __restrict__ Dinvg, float* __restrict__ scalars)
{
    __shared__ float shm[19200];   // 76.8 KB union
    int tid = threadIdx.x;
    if (blockIdx.x < 256) {
        float* Zl    = shm;            // 128*33 = 4224
        float* yredl = shm + 4224;     // 512
        { int e = blockIdx.x*64 + tid; if (tid < 64) psi2[e] = 0.f; }
        for (int e = tid; e < MM*DD; e += 256)
            Zl[(e>>5)*33 + (e&31)] = Zg[e];
        __syncthreads();
        int m = tid & 127, half = tid >> 7;
        float zr[DD];
        #pragma unroll
        for (int q = 0; q < DD; ++q) zr[q] = Zl[m*33 + q];
        float sm = sp[m];
        float y0=0.f, y1=0.f, y2=0.f, y3=0.f;
        int n0 = blockIdx.x*16 + half*8;
        for (int i = 0; i < 8; ++i) {
            int n = n0 + i;
            float L1n = L1p[n], bbn = bbp[n];
            const float4* pkn = pk4 + n*DD;
            float racc = 0.f, q1 = 0.f;
            #pragma unroll
            for (int q = 0; q < DD; ++q) {
                float4 v = pkn[q];
                float z = zr[q];
                racc = fmaf(v.x, z, racc);
                racc = fmaf(v.y, z*z, racc);
                float t = fmaf(v.z, z, v.w);
                q1 = fmaf(t, z, q1);
            }
            r_g[n*MM + m] = L1n + racc - sm;
            float p1 = __expf(fmaf(-0.5f, q1, bbn));
            float4 xo = *(const float4*)(Xm + (LTT+n)*QQ);
            y0 = fmaf(p1, xo.x, y0); y1 = fmaf(p1, xo.y, y1);
            y2 = fmaf(p1, xo.z, y2); y3 = fmaf(p1, xo.w, y3);
        }
        if (half == 0) {
            yredl[m*4+0]=y0; yredl[m*4+1]=y1; yredl[m*4+2]=y2; yredl[m*4+3]=y3;
        }
        __syncthreads();
        if (half == 1) {
            yredl[m*4+0]+=y0; yredl[m*4+1]+=y1; yredl[m*4+2]+=y2; yredl[m*4+3]+=y3;
        }
        __syncthreads();
        for (int e = tid; e < 512; e += 256) atomicAdd(&Yg[e], yredl[e]);
    } else {
        float* mat   = shm;            // 16896
        float* dinvb = shm + 16896;    // 2048
        float* red   = shm + 18944;    // 256
        for (int e = tid; e < 16384; e += 256) mat[(e>>7)*132 + (e&127)] = Kuu[e];
        __syncthreads();
        dev_chol(mat, tid);
        float ld = (tid < 128) ? logf(mat[tid*132 + tid]) : 0.f;
        red[tid] = ld; __syncthreads();
        for (int s = 128; s; s >>= 1) { if (tid < s) red[tid] += red[tid+s]; __syncthreads(); }
        if (tid == 0) scalars[0] = red[0];
        dev_dinv(mat, dinvb, tid);
        for (int e = tid; e < 16384; e += 256) Lg[e] = mat[(e>>7)*132 + (e&127)];
        for (int e = tid; e < 2048; e += 256) Dinvg[e] = dinvb[e];
    }
}

// ============ K3: psi2 — 1152 blocks, 2-way ILP, symmetric tiles ============
__global__ __launch_bounds__(256) void psi2_kernel(
    const _Float16* __restrict__ Zh, const float* __restrict__ r_g,
    const _Float16* __restrict__ bh, float* __restrict__ psi2)
{
    __shared__ float pacc[4][64][4];
    int tid = threadIdx.x;
    int w = tid >> 6, l = tid & 63, lm = l & 15, lg = l >> 4;
    int b = blockIdx.x;
    int nq = b / 36, t = b - nq*36;
    int kt = (int)(0.5f*(sqrtf(8.f*(float)t + 1.f) - 1.f));
    if ((kt+1)*(kt+2)/2 <= t) ++kt;
    else if (kt*(kt+1)/2 > t) --kt;
    int mt = t - ((kt*(kt+1))>>1);     // mt <= kt

    half8 Bf = ((const half8*)Zh)[(kt*16 + lm)*4 + lg];
    half8 Zm = ((const half8*)Zh)[(mt*16 + lm)*4 + lg];
    f32x4 z4; z4[0]=0.f; z4[1]=0.f; z4[2]=0.f; z4[3]=0.f;
    f32x4 acc0 = z4, acc1 = z4;
    int n0g = nq*128 + w*32;
    const float* rbase = r_g + (size_t)n0g*MM;
    const half8* bbase = (const half8*)bh + (size_t)n0g*4;
    for (int i = 0; i < 32; i += 2) {
        half8 bf0 = bbase[i*4 + lg];
        half8 bf1 = bbase[i*4 + 4 + lg];
        const float* rn0 = rbase + i*MM;
        f32x4 rm0 = *(const f32x4*)(rn0 + mt*16 + lg*4);
        f32x4 rm1 = *(const f32x4*)(rn0 + MM + mt*16 + lg*4);
        float rk0 = rn0[kt*16 + lm];
        float rk1 = rn0[MM + kt*16 + lm];
        half8 A0 = Zm * bf0;
        half8 A1 = Zm * bf1;
        f32x4 p0 = __builtin_amdgcn_mfma_f32_16x16x32_f16(A0, Bf, z4, 0, 0, 0);
        f32x4 p1 = __builtin_amdgcn_mfma_f32_16x16x32_f16(A1, Bf, z4, 0, 0, 0);
        acc0[0] += fexp2(p0[0] + rm0[0] + rk0);
        acc0[1] += fexp2(p0[1] + rm0[1] + rk0);
        acc0[2] += fexp2(p0[2] + rm0[2] + rk0);
        acc0[3] += fexp2(p0[3] + rm0[3] + rk0);
        acc1[0] += fexp2(p1[0] + rm1[0] + rk1);
        acc1[1] += fexp2(p1[1] + rm1[1] + rk1);
        acc1[2] += fexp2(p1[2] + rm1[2] + rk1);
        acc1[3] += fexp2(p1[3] + rm1[3] + rk1);
    }
    f32x4 acc;
    acc[0]=acc0[0]+acc1[0]; acc[1]=acc0[1]+acc1[1];
    acc[2]=acc0[2]+acc1[2]; acc[3]=acc0[3]+acc1[3];
    #pragma unroll
    for (int j = 0; j < 4; ++j) pacc[w][l][j] = acc[j];
    __syncthreads();
    {
        int ll = tid >> 2, j = tid & 3;
        float s = pacc[0][ll][j] + pacc[1][ll][j] + pacc[2][ll][j] + pacc[3][ll][j];
        int row = mt*16 + (ll >> 4)*4 + j;
        int col = kt*16 + (ll & 15);
        atomicAdd(&psi2[row*MM + col], s);
        if (mt != kt) atomicAdd(&psi2[col*MM + row], s);
    }
}

// ============ K4: block0 = chol(G)+Y-solve; blocks 1-16 = trace; elect final ============
__global__ __launch_bounds__(256) void cholG_kernel(
    const float* __restrict__ Kuu, const float* __restrict__ psi2,
    const float* __restrict__ Yg, const float* __restrict__ Lg,
    const float* __restrict__ Dinvg, const float* __restrict__ varp,
    const float* __restrict__ sumsP,
    float* __restrict__ scalars, int* __restrict__ cnt, float* __restrict__ out)
{
    __shared__ float mat[128*132];
    __shared__ float dinvb[8*256];
    __shared__ float rhs[128*8];
    __shared__ float tmp[128];
    __shared__ float red[256];
    int tid = threadIdx.x;
    if (blockIdx.x == 0) {
        for (int e = tid; e < 16384; e += 256)
            mat[(e>>7)*132 + (e&127)] = Kuu[e] + (1.0f/SIG2)*psi2[e];
        __syncthreads();
        dev_chol(mat, tid);
        float ld = (tid < 128) ? logf(mat[tid*132 + tid]) : 0.f;
        red[tid] = ld; __syncthreads();
        for (int s = 128; s; s >>= 1) { if (tid < s) red[tid] += red[tid+s]; __syncthreads(); }
        if (tid == 0) scalars[1] = red[0];
        dev_dinv(mat, dinvb, tid);
        if (tid < 256) { rhs[tid] = Yg[tid]; rhs[tid+256] = Yg[tid+256]; }
        __syncthreads();
        dev_solve<4>(mat, dinvb, tmp, rhs, tid);
        float c2 = rhs[tid]*rhs[tid] + rhs[tid+256]*rhs[tid+256];
        red[tid] = c2; __syncthreads();
        for (int s = 128; s; s >>= 1) { if (tid < s) red[tid] += red[tid+s]; __syncthreads(); }
        if (tid == 0) scalars[2] = red[0];
    } else {
        int c0 = (blockIdx.x - 1) * 8;
        for (int e = tid; e < 16384; e += 256) mat[(e>>7)*132 + (e&127)] = Lg[e];
        for (int e = tid; e < 2048; e += 256) dinvb[e] = Dinvg[e];
        for (int e = tid; e < 1024; e += 256) {
            int i = e >> 3, cc = e & 7;
            rhs[e] = (i == c0 + cc) ? 1.0f : 0.0f;
        }
        __syncthreads();
        dev_bsolve<8>(mat, dinvb, tmp, rhs, tid);
        int i = tid & 127, cp = tid >> 7;
        float vv0=0.f, vv1=0.f, vv2=0.f, vv3=0.f;
        for (int j = 0; j < 128; ++j) {
            float pj = psi2[j*MM + i];   // symmetric -> coalesced row read
            vv0 = fmaf(pj, rhs[j*8 + cp*4 + 0], vv0);
            vv1 = fmaf(pj, rhs[j*8 + cp*4 + 1], vv1);
            vv2 = fmaf(pj, rhs[j*8 + cp*4 + 2], vv2);
            vv3 = fmaf(pj, rhs[j*8 + cp*4 + 3], vv3);
        }
        float part = rhs[i*8 + cp*4 + 0]*vv0 + rhs[i*8 + cp*4 + 1]*vv1
                   + rhs[i*8 + cp*4 + 2]*vv2 + rhs[i*8 + cp*4 + 3]*vv3;
        red[tid] = part; __syncthreads();
        for (int s = 128; s; s >>= 1) { if (tid < s) red[tid] += red[tid+s]; __syncthreads(); }
        if (tid == 0) atomicAdd(&scalars[3], red[0]);
    }
    if (tid == 0) {
        __threadfence();
        int old = atomicAdd(cnt, 1);
        if (old == 16) {
            float ldK  = scalars[0];
            float ldG  = atomicAdd(&scalars[1], 0.0f);
            float c2s  = atomicAdd(&scalars[2], 0.0f);
            float trr  = atomicAdd(&scalars[3], 0.0f);
            float s1=0.f, s2=0.f, s3=0.f;
            for (int b2 = 0; b2 < 16; ++b2) {
                s1 += sumsP[b2*3+0]; s2 += sumsP[b2*3+1]; s3 += sumsP[b2*3+2];
            }
            float var = varp[0];
            float trAAT   = trr / SIG2;
            float logdetB = 2.0f * (ldG - ldK);
            float sumc2   = c2s / (SIG2*SIG2);
            float psi0    = (float)NN * var;
            const float LOG2PI = 1.837877066409345f;
            float NQf = (float)NQ;
            float bound = -0.5f*NQf*(LOG2PI + logf(SIG2));
            bound += -0.5f/SIG2 * s1;
            bound += -0.5f*(float)QQ*(psi0/SIG2 - trAAT);
            bound += -0.5f*(float)QQ*logdetB;
            bound += 0.5f*sumc2;
            bound += 0.5f*s2 + 0.5f*NQf*LOG2PI;
            bound += -(float)(LTT*QQ)*LOG2PI - 0.5f*s3;
            out[0] = bound;
        }
    }
}

extern "C" void kernel_launch(void* const* d_in, const int* in_sizes, int n_in,
                              void* d_out, int out_size, void* d_ws, size_t ws_size,
                              hipStream_t stream)
{
    (void)in_sizes; (void)n_in; (void)out_size; (void)ws_size;
    const float* Xm   = (const float*)d_in[0];
    const float* Xv   = (const float*)d_in[1];
    const float* Zg   = (const float*)d_in[2];
    const float* ls   = (const float*)d_in[3];
    const float* varp = (const float*)d_in[4];

    float* p = (float*)d_ws;
    float4*   pk4   = (float4*)p;       p += NN*DD*4;
    float*    r_g   = p;                p += NN*MM;
    _Float16* bh    = (_Float16*)p;     p += NN*DD/2;
    _Float16* Zh    = (_Float16*)p;     p += MM*DD/2;
    float*    L1p   = p;                p += NN;
    float*    bbp   = p;                p += NN;
    float*    sp    = p;                p += MM;
    float*    Kuu   = p;                p += MM*MM;
    float*    Lg    = p;                p += MM*MM;
    float*    Dinvg = p;                p += 2048;
    float*    psi2  = p;                p += MM*MM;
    float*    Yg    = p;                p += 512;
    float*    sumsP = p;                p += 64;
    float*    scalars = p;              p += 8;
    int*      cnt   = (int*)p;          p += 4;

    prepstatic_kernel<<<81, 256, 0, stream>>>(Xm, Xv, Zg, ls, varp,
                                              pk4, bh, L1p, bbp, sumsP, Kuu, sp, Zh,
                                              Yg, scalars, cnt);
    k1chol_kernel<<<257, 256, 0, stream>>>(Xm, Zg, pk4, L1p, bbp, sp, r_g, Yg, psi2,
                                           Kuu, Lg, Dinvg, scalars);
    psi2_kernel<<<1152, 256, 0, stream>>>(Zh, r_g, bh, psi2);
    cholG_kernel<<<17, 256, 0, stream>>>(Kuu, psi2, Yg, Lg, Dinvg, varp, sumsP,
                                         scalars, cnt, (float*)d_out);
}

// Round 9
// 177.535 us; speedup vs baseline: 1.2845x; 1.0564x over previous
//
#include <hip/hip_runtime.h>

#define NN   4096
#define NQ   (NN*4)
#define QQ   4
#define LTT  8
#define DD   32
#define MM   128
#define SIG2 0.001f
#define JIT  1e-5f
#define LOG2E 1.4426950408889634f

typedef _Float16 half8 __attribute__((ext_vector_type(8)));
typedef float    f32x4 __attribute__((ext_vector_type(4)));

__device__ __forceinline__ float fexp2(float x) { return exp2f(x); }

__device__ __forceinline__ float rlane(float v, int l) {
    return __uint_as_float(__builtin_amdgcn_readlane(__float_as_uint(v), l));
}

// ============ prep (blocks 0-15) + Kuu (16-79) + sp/Zh/zeroing (80) ============
__global__ __launch_bounds__(256) void prepstatic_kernel(
    const float* __restrict__ Xm, const float* __restrict__ Xv,
    const float* __restrict__ Zg, const float* __restrict__ ls,
    const float* __restrict__ varp,
    float4* __restrict__ pk4, _Float16* __restrict__ bh,
    float* __restrict__ L1p, float* __restrict__ bbp, float* __restrict__ sumsP,
    float* __restrict__ Kuu, float* __restrict__ sp, _Float16* __restrict__ Zh,
    float* __restrict__ Yg, float* __restrict__ scalars, int* __restrict__ cnt)
{
    int b = blockIdx.x, tid = threadIdx.x;
    if (b < 16) {
        __shared__ float ra[256], rb[256], rc[256];
        int n = b*256 + tid;
        float var = varp[0];
        float slog2 = 0.f, slog1 = 0.f, T1 = 0.f, c0 = 0.f;
        #pragma unroll 8
        for (int q = 0; q < DD; ++q) {
            float xm = Xm[n*QQ + q];
            float xv = Xv[n*QQ + q];
            float l  = ls[q];
            float l2 = l*l;
            float a    = 1.0f / (2.0f*xv + l2);
            float dinv = 1.0f / (l2 + xv);
            float4 v;
            v.x = LOG2E * a * xm;
            v.y = LOG2E * (-0.25f * a);
            v.z = dinv;
            v.w = -2.0f * dinv * xm;
            pk4[n*DD + q] = v;
            bh[n*DD + q] = (_Float16)(0.5f * LOG2E * (1.0f/l2 - a));
            slog2 += log1pf(2.0f*xv/l2);
            slog1 += log1pf(xv/l2);
            T1    += a*xm*xm;
            c0    += dinv*xm*xm;
        }
        L1p[n] = 0.5f * LOG2E * (2.0f*logf(var) - 0.5f*slog2 - T1);
        bbp[n] = logf(var) - 0.5f*slog1 - 0.5f*c0;
        float s1 = 0.f, s2 = 0.f, s3 = 0.f;
        #pragma unroll
        for (int c = 0; c < QQ; ++c) {
            float mo = Xm[(n+LTT)*QQ + c];
            float vo = Xv[(n+LTT)*QQ + c];
            s1 += vo + mo*mo;
            s2 += logf(vo);
        }
        if (n < LTT) {
            #pragma unroll
            for (int c = 0; c < QQ; ++c) {
                float mb = Xm[n*QQ+c], vb = Xv[n*QQ+c];
                s3 += mb*mb + vb;
            }
        }
        ra[tid]=s1; rb[tid]=s2; rc[tid]=s3;
        __syncthreads();
        for (int s = 128; s; s >>= 1) {
            if (tid < s) { ra[tid]+=ra[tid+s]; rb[tid]+=rb[tid+s]; rc[tid]+=rc[tid+s]; }
            __syncthreads();
        }
        if (tid == 0) { sumsP[b*3+0]=ra[0]; sumsP[b*3+1]=rb[0]; sumsP[b*3+2]=rc[0]; }
    } else if (b < 80) {
        int idx = (b-16)*256 + tid;
        int i = idx >> 7, j = idx & 127;
        float var = varp[0];
        float s = 0.f;
        for (int q = 0; q < DD; ++q) {
            float l = ls[q];
            float d = (Zg[i*DD+q] - Zg[j*DD+q]) / l;
            s += d*d;
        }
        float v = var * __expf(-0.5f*s);
        if (i == j) v += JIT;
        Kuu[idx] = v;
    } else {
        if (tid < MM) {
            float s = 0.f;
            for (int q = 0; q < DD; ++q) {
                float l = ls[q]; float z = Zg[tid*DD+q];
                s += z*z / (4.0f*l*l);
            }
            sp[tid] = LOG2E * s;
        }
        for (int e = tid; e < MM*DD; e += 256) Zh[e] = (_Float16)Zg[e];
        for (int e = tid; e < 512; e += 256) Yg[e] = 0.f;
        if (tid < 8) scalars[tid] = 0.f;
        if (tid == 0) *cnt = 0;
    }
}

// ============ K2: k1 — r[n,m] + Yg atomics + psi2 zeroing ============
__global__ __launch_bounds__(256) void k1_kernel(
    const float* __restrict__ Xm, const float* __restrict__ Zg,
    const float4* __restrict__ pk4, const float* __restrict__ L1p,
    const float* __restrict__ bbp, const float* __restrict__ sp,
    float* __restrict__ r_g, float* __restrict__ Yg, float* __restrict__ psi2)
{
    __shared__ float Zl[MM*33];
    __shared__ float yredl[MM*QQ];
    int tid = threadIdx.x;
    { int e = blockIdx.x*64 + tid; if (tid < 64) psi2[e] = 0.f; }
    for (int e = tid; e < MM*DD; e += 256)
        Zl[(e>>5)*33 + (e&31)] = Zg[e];
    __syncthreads();
    int m = tid & 127, half = tid >> 7;
    float zr[DD];
    #pragma unroll
    for (int q = 0; q < DD; ++q) zr[q] = Zl[m*33 + q];
    float sm = sp[m];
    float y0=0.f, y1=0.f, y2=0.f, y3=0.f;
    int n0 = blockIdx.x*16 + half*8;
    for (int i = 0; i < 8; ++i) {
        int n = n0 + i;
        float L1n = L1p[n], bbn = bbp[n];
        const float4* pkn = pk4 + n*DD;
        float racc = 0.f, q1 = 0.f;
        #pragma unroll
        for (int q = 0; q < DD; ++q) {
            float4 v = pkn[q];
            float z = zr[q];
            racc = fmaf(v.x, z, racc);
            racc = fmaf(v.y, z*z, racc);
            float t = fmaf(v.z, z, v.w);
            q1 = fmaf(t, z, q1);
        }
        r_g[n*MM + m] = L1n + racc - sm;
        float p1 = __expf(fmaf(-0.5f, q1, bbn));
        float4 xo = *(const float4*)(Xm + (LTT+n)*QQ);
        y0 = fmaf(p1, xo.x, y0); y1 = fmaf(p1, xo.y, y1);
        y2 = fmaf(p1, xo.z, y2); y3 = fmaf(p1, xo.w, y3);
    }
    if (half == 0) {
        yredl[m*4+0]=y0; yredl[m*4+1]=y1; yredl[m*4+2]=y2; yredl[m*4+3]=y3;
    }
    __syncthreads();
    if (half == 1) {
        yredl[m*4+0]+=y0; yredl[m*4+1]+=y1; yredl[m*4+2]+=y2; yredl[m*4+3]+=y3;
    }
    __syncthreads();
    for (int e = tid; e < 512; e += 256) atomicAdd(&Yg[e], yredl[e]);
}

// ============ linalg device functions, LDS stride 132 ============
template<int NT>
__device__ __forceinline__ void dev_chol(float* mat, int tid)
{
    int wv = tid >> 6, ln = tid & 63;
    for (int p = 0; p < 8; ++p) {
        int base = p*16;
        if (wv == 0) {
            int r0 = base + ln, r1 = r0 + 64;
            bool h0 = r0 < 128, h1 = r1 < 128;
            float a0[16], a1[16];
            #pragma unroll
            for (int c = 0; c < 16; ++c) {
                a0[c] = h0 ? mat[r0*132 + base + c] : 0.f;
                a1[c] = h1 ? mat[r1*132 + base + c] : 0.f;
            }
            #pragma unroll
            for (int kk = 0; kk < 16; ++kk) {
                float d   = rlane(a0[kk], kk);
                float rdk = rsqrtf(d);
                float sq  = d * rdk;
                a0[kk] = (ln == kk) ? sq : a0[kk] * rdk;
                a1[kk] *= rdk;
                #pragma unroll
                for (int j = kk+1; j < 16; ++j) {
                    float ljv = rlane(a0[kk], j);
                    a0[j] = fmaf(-a0[kk], ljv, a0[j]);
                    a1[j] = fmaf(-a1[kk], ljv, a1[j]);
                }
            }
            #pragma unroll
            for (int c = 0; c < 16; ++c) {
                if (h0) mat[r0*132 + base + c] = a0[c];
                if (h1) mat[r1*132 + base + c] = a1[c];
            }
        }
        __syncthreads();
        int S = 112 - base;
        if (S > 0) {
            int T = S >> 2, nb = base + 16;
            int nT = (T*(T+1)) >> 1;
            for (int t = tid; t < nT; t += NT) {
                int ti = (int)(0.5f*(sqrtf(8.f*(float)t + 1.f) - 1.f));
                if ((ti+1)*(ti+2)/2 <= t) ++ti;
                else if (ti*(ti+1)/2 > t) --ti;
                int tj = t - ((ti*(ti+1))>>1);
                int i0 = nb + ti*4, j0 = nb + tj*4;
                float ac[4][4];
                #pragma unroll
                for (int r = 0; r < 4; ++r)
                    #pragma unroll
                    for (int s = 0; s < 4; ++s) ac[r][s] = mat[(i0+r)*132 + j0 + s];
                #pragma unroll
                for (int c4 = 0; c4 < 4; ++c4) {
                    float4 av[4], bv[4];
                    #pragma unroll
                    for (int r = 0; r < 4; ++r) {
                        av[r] = *(const float4*)&mat[(i0+r)*132 + base + c4*4];
                        bv[r] = *(const float4*)&mat[(j0+r)*132 + base + c4*4];
                    }
                    #pragma unroll
                    for (int r = 0; r < 4; ++r)
                        #pragma unroll
                        for (int s = 0; s < 4; ++s)
                            ac[r][s] -= av[r].x*bv[s].x + av[r].y*bv[s].y
                                      + av[r].z*bv[s].z + av[r].w*bv[s].w;
                }
                #pragma unroll
                for (int r = 0; r < 4; ++r)
                    #pragma unroll
                    for (int s = 0; s < 4; ++s) mat[(i0+r)*132 + j0 + s] = ac[r][s];
            }
        }
        __syncthreads();
    }
}

template<int NT>
__device__ __forceinline__ void dev_dinv(const float* mat, float* dinvb, int tid)
{
    int wv = tid >> 6, ln = tid & 63;
    if (ln < 16) {
        int c = ln;
        for (int bd = wv; bd < 8; bd += NT/64) {
            int base = bd*16;
            float x[16];
            #pragma unroll
            for (int i = 0; i < 16; ++i) {
                float dii = mat[(base+i)*132 + base + i];
                float s = 0.f;
                #pragma unroll
                for (int j = 0; j < i; ++j) s += mat[(base+i)*132 + base + j] * x[j];
                float v;
                if (i < c) v = 0.f;
                else if (i == c) v = 1.0f / dii;
                else v = -s / dii;
                x[i] = v;
            }
            #pragma unroll
            for (int i = 0; i < 16; ++i) dinvb[bd*256 + i*16 + c] = x[i];
        }
    }
    __syncthreads();
}

template<int C>
__device__ __forceinline__ void dev_bsolve(const float* mat, const float* dinvb,
                                           float* tmp, float* rhs, int tid)
{
    const int AT = 16*C;
    int r = tid / C, cc = tid % C;
    for (int bi = 7; bi >= 0; --bi) {
        float acc = 0.f;
        if (tid < AT) {
            acc = rhs[(bi*16+r)*C + cc];
            for (int bj = bi+1; bj < 8; ++bj) {
                #pragma unroll
                for (int kk = 0; kk < 16; ++kk)
                    acc -= mat[(bj*16+kk)*132 + bi*16 + r] * rhs[(bj*16+kk)*C + cc];
            }
        }
        __syncthreads();
        if (tid < AT) tmp[r*C + cc] = acc;
        __syncthreads();
        if (tid < AT) {
            float w = 0.f;
            #pragma unroll
            for (int kk = 0; kk < 16; ++kk)
                w += dinvb[bi*256 + kk*16 + r] * tmp[kk*C + cc];   // Dinv^T
            rhs[(bi*16+r)*C + cc] = w;
        }
        __syncthreads();
    }
}

// ============ K3: block0 = chol(Kuu); blocks 1-1152 = psi2 (512 thr) ============
__global__ __launch_bounds__(512) void psi2chol_kernel(
    const _Float16* __restrict__ Zh, const float* __restrict__ r_g,
    const _Float16* __restrict__ bh, float* __restrict__ psi2,
    const float* __restrict__ Kuu, float* __restrict__ Lg,
    float* __restrict__ Dinvg, float* __restrict__ scalars)
{
    __shared__ float shm[19456];   // 77.8 KB
    int tid = threadIdx.x;
    if (blockIdx.x == 0) {
        float* mat   = shm;            // 16896
        float* dinvb = shm + 16896;    // 2048
        float* red   = shm + 18944;    // 512
        for (int e = tid; e < 16384; e += 512) mat[(e>>7)*132 + (e&127)] = Kuu[e];
        __syncthreads();
        dev_chol<512>(mat, tid);
        red[tid] = (tid < 128) ? logf(mat[tid*132 + tid]) : 0.f;
        __syncthreads();
        for (int s = 256; s; s >>= 1) { if (tid < s) red[tid] += red[tid+s]; __syncthreads(); }
        if (tid == 0) scalars[0] = red[0];
        dev_dinv<512>(mat, dinvb, tid);
        for (int e = tid; e < 16384; e += 512) Lg[e] = mat[(e>>7)*132 + (e&127)];
        for (int e = tid; e < 2048; e += 512) Dinvg[e] = dinvb[e];
    } else {
        float (*pacc)[64][4] = (float(*)[64][4])shm;   // 8*64*4
        int w = tid >> 6, l = tid & 63, lm = l & 15, lg = l >> 4;
        int b = blockIdx.x - 1;
        int t = b % 36, nq = b / 36;
        int kt = (int)(0.5f*(sqrtf(8.f*(float)t + 1.f) - 1.f));
        if ((kt+1)*(kt+2)/2 <= t) ++kt;
        else if (kt*(kt+1)/2 > t) --kt;
        int mt = t - ((kt*(kt+1))>>1);     // mt <= kt

        half8 Bf = ((const half8*)Zh)[(kt*16 + lm)*4 + lg];
        half8 Zm = ((const half8*)Zh)[(mt*16 + lm)*4 + lg];
        f32x4 z4; z4[0]=0.f; z4[1]=0.f; z4[2]=0.f; z4[3]=0.f;
        f32x4 acc0 = z4, acc1 = z4;
        int n0g = nq*128 + w*16;
        const float* rbase = r_g + (size_t)n0g*MM;
        const half8* bbase = (const half8*)bh + (size_t)n0g*4;
        for (int i = 0; i < 16; i += 2) {
            half8 bf0 = bbase[i*4 + lg];
            half8 bf1 = bbase[i*4 + 4 + lg];
            const float* rn0 = rbase + i*MM;
            f32x4 rm0 = *(const f32x4*)(rn0 + mt*16 + lg*4);
            f32x4 rm1 = *(const f32x4*)(rn0 + MM + mt*16 + lg*4);
            float rk0 = rn0[kt*16 + lm];
            float rk1 = rn0[MM + kt*16 + lm];
            half8 A0 = Zm * bf0;
            half8 A1 = Zm * bf1;
            f32x4 p0 = __builtin_amdgcn_mfma_f32_16x16x32_f16(A0, Bf, z4, 0, 0, 0);
            f32x4 p1 = __builtin_amdgcn_mfma_f32_16x16x32_f16(A1, Bf, z4, 0, 0, 0);
            acc0[0] += fexp2(p0[0] + rm0[0] + rk0);
            acc0[1] += fexp2(p0[1] + rm0[1] + rk0);
            acc0[2] += fexp2(p0[2] + rm0[2] + rk0);
            acc0[3] += fexp2(p0[3] + rm0[3] + rk0);
            acc1[0] += fexp2(p1[0] + rm1[0] + rk1);
            acc1[1] += fexp2(p1[1] + rm1[1] + rk1);
            acc1[2] += fexp2(p1[2] + rm1[2] + rk1);
            acc1[3] += fexp2(p1[3] + rm1[3] + rk1);
        }
        #pragma unroll
        for (int j = 0; j < 4; ++j) pacc[w][l][j] = acc0[j] + acc1[j];
        __syncthreads();
        if (tid < 256) {
            int ll = tid >> 2, j = tid & 3;
            float s = 0.f;
            #pragma unroll
            for (int ww = 0; ww < 8; ++ww) s += pacc[ww][ll][j];
            int row = mt*16 + (ll >> 4)*4 + j;
            int col = kt*16 + (ll & 15);
            atomicAdd(&psi2[row*MM + col], s);
            if (mt != kt) atomicAdd(&psi2[col*MM + row], s);
        }
    }
}

// ============ K4: block0 = chol(G)+wave-solve; blocks 1-16 = trace; elect final ============
__global__ __launch_bounds__(512) void cholG_kernel(
    const float* __restrict__ Kuu, const float* __restrict__ psi2,
    const float* __restrict__ Yg, const float* __restrict__ Lg,
    const float* __restrict__ Dinvg, const float* __restrict__ varp,
    const float* __restrict__ sumsP,
    float* __restrict__ scalars, int* __restrict__ cnt, float* __restrict__ out)
{
    __shared__ float mat[128*132];
    __shared__ float dinvb[8*256];
    __shared__ float rhs[128*8];
    __shared__ float tmp[128];
    __shared__ float red[512];
    int tid = threadIdx.x;
    if (blockIdx.x == 0) {
        for (int e = tid; e < 16384; e += 512)
            mat[(e>>7)*132 + (e&127)] = Kuu[e] + (1.0f/SIG2)*psi2[e];
        __syncthreads();
        dev_chol<512>(mat, tid);
        red[tid] = (tid < 128) ? logf(mat[tid*132 + tid]) : 0.f;
        __syncthreads();
        for (int s = 256; s; s >>= 1) { if (tid < s) red[tid] += red[tid+s]; __syncthreads(); }
        if (tid == 0) scalars[1] = red[0];
        dev_dinv<512>(mat, dinvb, tid);
        rhs[tid & 511] = Yg[tid & 511];
        __syncthreads();
        // ---- wave-local forward solve, 4 RHS ----
        if (tid < 64) {
            int r = tid >> 2, cc = tid & 3;
            for (int bi = 0; bi < 8; ++bi) {
                float a0 = rhs[(bi*16+r)*4 + cc], a1 = 0.f, a2 = 0.f, a3 = 0.f;
                for (int bk = 0; bk < bi; ++bk) {
                    const float* mrow = &mat[(bi*16+r)*132 + bk*16];
                    const float* rb   = &rhs[bk*64 + cc];
                    #pragma unroll
                    for (int kk = 0; kk < 16; kk += 4) {
                        a0 = fmaf(-mrow[kk+0], rb[(kk+0)*4], a0);
                        a1 = fmaf(-mrow[kk+1], rb[(kk+1)*4], a1);
                        a2 = fmaf(-mrow[kk+2], rb[(kk+2)*4], a2);
                        a3 = fmaf(-mrow[kk+3], rb[(kk+3)*4], a3);
                    }
                }
                float acc = (a0+a1)+(a2+a3);
                float w = 0.f;
                #pragma unroll
                for (int kk = 0; kk < 16; ++kk)
                    w += dinvb[bi*256 + r*16 + kk] * __shfl(acc, kk*4 + cc, 64);
                rhs[(bi*16+r)*4 + cc] = w;
            }
        }
        __syncthreads();
        { float v = rhs[tid & 511]; red[tid] = v*v; }
        __syncthreads();
        for (int s = 256; s; s >>= 1) { if (tid < s) red[tid] += red[tid+s]; __syncthreads(); }
        if (tid == 0) scalars[2] = red[0];
    } else {
        int c0 = (blockIdx.x - 1) * 8;
        for (int e = tid; e < 16384; e += 512) mat[(e>>7)*132 + (e&127)] = Lg[e];
        for (int e = tid; e < 2048; e += 512) dinvb[e] = Dinvg[e];
        for (int e = tid; e < 1024; e += 512) {
            int i = e >> 3, cc = e & 7;
            rhs[e] = (i == c0 + cc) ? 1.0f : 0.0f;
        }
        __syncthreads();
        dev_bsolve<8>(mat, dinvb, tmp, rhs, tid);
        int i = tid & 127, cp = (tid >> 7) & 1, jh = tid >> 8;
        float vv0=0.f, vv1=0.f, vv2=0.f, vv3=0.f;
        for (int j = jh*64; j < jh*64 + 64; ++j) {
            float pj = psi2[j*MM + i];   // symmetric -> coalesced row read
            vv0 = fmaf(pj, rhs[j*8 + cp*4 + 0], vv0);
            vv1 = fmaf(pj, rhs[j*8 + cp*4 + 1], vv1);
            vv2 = fmaf(pj, rhs[j*8 + cp*4 + 2], vv2);
            vv3 = fmaf(pj, rhs[j*8 + cp*4 + 3], vv3);
        }
        float part = rhs[i*8 + cp*4 + 0]*vv0 + rhs[i*8 + cp*4 + 1]*vv1
                   + rhs[i*8 + cp*4 + 2]*vv2 + rhs[i*8 + cp*4 + 3]*vv3;
        red[tid] = part;
        __syncthreads();
        for (int s = 256; s; s >>= 1) { if (tid < s) red[tid] += red[tid+s]; __syncthreads(); }
        if (tid == 0) atomicAdd(&scalars[3], red[0]);
    }
    if (tid == 0) {
        __threadfence();
        int old = atomicAdd(cnt, 1);
        if (old == 16) {
            float ldK  = scalars[0];
            float ldG  = atomicAdd(&scalars[1], 0.0f);
            float c2s  = atomicAdd(&scalars[2], 0.0f);
            float trr  = atomicAdd(&scalars[3], 0.0f);
            float s1=0.f, s2=0.f, s3=0.f;
            for (int b2 = 0; b2 < 16; ++b2) {
                s1 += sumsP[b2*3+0]; s2 += sumsP[b2*3+1]; s3 += sumsP[b2*3+2];
            }
            float var = varp[0];
            float trAAT   = trr / SIG2;
            float logdetB = 2.0f * (ldG - ldK);
            float sumc2   = c2s / (SIG2*SIG2);
            float psi0    = (float)NN * var;
            const float LOG2PI = 1.837877066409345f;
            float NQf = (float)NQ;
            float bound = -0.5f*NQf*(LOG2PI + logf(SIG2));
            bound += -0.5f/SIG2 * s1;
            bound += -0.5f*(float)QQ*(psi0/SIG2 - trAAT);
            bound += -0.5f*(float)QQ*logdetB;
            bound += 0.5f*sumc2;
            bound += 0.5f*s2 + 0.5f*NQf*LOG2PI;
            bound += -(float)(LTT*QQ)*LOG2PI - 0.5f*s3;
            out[0] = bound;
        }
    }
}

extern "C" void kernel_launch(void* const* d_in, const int* in_sizes, int n_in,
                              void* d_out, int out_size, void* d_ws, size_t ws_size,
                              hipStream_t stream)
{
    (void)in_sizes; (void)n_in; (void)out_size; (void)ws_size;
    const float* Xm   = (const float*)d_in[0];
    const float* Xv   = (const float*)d_in[1];
    const float* Zg   = (const float*)d_in[2];
    const float* ls   = (const float*)d_in[3];
    const float* varp = (const float*)d_in[4];

    float* p = (float*)d_ws;
    float4*   pk4   = (float4*)p;       p += NN*DD*4;
    float*    r_g   = p;                p += NN*MM;
    _Float16* bh    = (_Float16*)p;     p += NN*DD/2;
    _Float16* Zh    = (_Float16*)p;     p += MM*DD/2;
    float*    L1p   = p;                p += NN;
    float*    bbp   = p;                p += NN;
    float*    sp    = p;                p += MM;
    float*    Kuu   = p;                p += MM*MM;
    float*    Lg    = p;                p += MM*MM;
    float*    Dinvg = p;                p += 2048;
    float*    psi2  = p;                p += MM*MM;
    float*    Yg    = p;                p += 512;
    float*    sumsP = p;                p += 64;
    float*    scalars = p;              p += 8;
    int*      cnt   = (int*)p;          p += 4;

    prepstatic_kernel<<<81, 256, 0, stream>>>(Xm, Xv, Zg, ls, varp,
                                              pk4, bh, L1p, bbp, sumsP, Kuu, sp, Zh,
                                              Yg, scalars, cnt);
    k1_kernel<<<256, 256, 0, stream>>>(Xm, Zg, pk4, L1p, bbp, sp, r_g, Yg, psi2);
    psi2chol_kernel<<<1153, 512, 0, stream>>>(Zh, r_g, bh, psi2, Kuu, Lg, Dinvg, scalars);
    cholG_kernel<<<17, 512, 0, stream>>>(Kuu, psi2, Yg, Lg, Dinvg, varp, sumsP,
                                         scalars, cnt, (float*)d_out);
}

// Round 10
// 165.181 us; speedup vs baseline: 1.3805x; 1.0748x over previous
//
#include <hip/hip_runtime.h>

#define NN   4096
#define NQ   (NN*4)
#define QQ   4
#define LTT  8
#define DD   32
#define MM   128
#define SIG2 0.001f
#define JIT  1e-5f
#define LOG2E 1.4426950408889634f

typedef _Float16 half8 __attribute__((ext_vector_type(8)));
typedef float    f32x4 __attribute__((ext_vector_type(4)));

__device__ __forceinline__ float fexp2(float x) { return exp2f(x); }

__device__ __forceinline__ float rlane(float v, int l) {
    return __uint_as_float(__builtin_amdgcn_readlane(__float_as_uint(v), l));
}

// ============ K1: blocks 0-255 = prep+k1 fused; 256-319 = Kuu; 320 = Zh ============
__global__ __launch_bounds__(256) void k1_kernel(
    const float* __restrict__ Xm, const float* __restrict__ Xv,
    const float* __restrict__ Zg, const float* __restrict__ ls,
    const float* __restrict__ varp,
    _Float16* __restrict__ bh, float* __restrict__ r_g, float* __restrict__ Yg,
    _Float16* __restrict__ Zh, float* __restrict__ Kuu, float* __restrict__ scalars)
{
    int b = blockIdx.x, tid = threadIdx.x;
    if (b < 256) {
        __shared__ float Zl[MM*33];
        __shared__ float pkl[16][DD][4];
        __shared__ float L1l[16], bbl[16];
        __shared__ float lsq[DD];
        __shared__ float yredl[MM*QQ];
        __shared__ float redl[48];
        for (int e = tid; e < MM*DD; e += 256)
            Zl[(e>>5)*33 + (e&31)] = Zg[e];
        if (tid < DD) { float l = ls[tid]; lsq[tid] = 1.0f/(l*l); }
        __syncthreads();
        int n0 = b*16;
        float var  = varp[0];
        float logv = logf(var);
        // ---- prep: thread -> (nl = tid>>4, q = (tid&15)*2 + t2) ----
        int nl = tid >> 4;
        int n  = n0 + nl;
        float slog2 = 0.f, slog1 = 0.f, T1 = 0.f, c0 = 0.f;
        #pragma unroll
        for (int t2 = 0; t2 < 2; ++t2) {
            int q = (tid & 15)*2 + t2;
            float xm  = Xm[n*QQ + q];
            float xv  = Xv[n*QQ + q];
            float il2 = lsq[q];
            float l2  = 1.0f / il2;
            float a    = 1.0f / (2.0f*xv + l2);
            float dinv = 1.0f / (l2 + xv);
            pkl[nl][q][0] = LOG2E * a * xm;
            pkl[nl][q][1] = LOG2E * (-0.25f * a);
            pkl[nl][q][2] = dinv;
            pkl[nl][q][3] = -2.0f * dinv * xm;
            bh[n*DD + q] = (_Float16)(0.5f * LOG2E * (il2 - a));
            slog2 += log1pf(2.0f*xv*il2);
            slog1 += log1pf(xv*il2);
            T1    += a*xm*xm;
            c0    += dinv*xm*xm;
        }
        float s1 = 0.f, s2 = 0.f, s3 = 0.f;
        if ((tid & 15) < 4) {
            int c = tid & 3;
            float mo = Xm[(n+LTT)*QQ + c];
            float vo = Xv[(n+LTT)*QQ + c];
            s1 = vo + mo*mo;
            s2 = logf(vo);
            if (n < LTT) {
                float mb = Xm[n*QQ + c], vb = Xv[n*QQ + c];
                s3 = mb*mb + vb;
            }
        }
        #pragma unroll
        for (int off = 1; off < 16; off <<= 1) {
            slog2 += __shfl_xor(slog2, off, 64);
            slog1 += __shfl_xor(slog1, off, 64);
            T1    += __shfl_xor(T1, off, 64);
            c0    += __shfl_xor(c0, off, 64);
            s1    += __shfl_xor(s1, off, 64);
            s2    += __shfl_xor(s2, off, 64);
            s3    += __shfl_xor(s3, off, 64);
        }
        if ((tid & 15) == 0) {
            L1l[nl] = 0.5f * LOG2E * (2.0f*logv - 0.5f*slog2 - T1);
            bbl[nl] = logv - 0.5f*slog1 - 0.5f*c0;
            redl[nl] = s1; redl[16+nl] = s2; redl[32+nl] = s3;
        }
        __syncthreads();
        if (tid == 0) {
            float a1=0.f, a2=0.f, a3=0.f;
            for (int i2 = 0; i2 < 16; ++i2) { a1+=redl[i2]; a2+=redl[16+i2]; a3+=redl[32+i2]; }
            atomicAdd(&scalars[4], a1);
            atomicAdd(&scalars[5], a2);
            atomicAdd(&scalars[6], a3);
        }
        // ---- k1 main ----
        int m = tid & 127, half = tid >> 7;
        float zr[DD];
        #pragma unroll
        for (int q = 0; q < DD; ++q) zr[q] = Zl[m*33 + q];
        float sm = 0.f;
        #pragma unroll
        for (int q = 0; q < DD; ++q) sm = fmaf(zr[q]*zr[q], lsq[q], sm);
        sm *= 0.25f * LOG2E;
        float y0=0.f, y1=0.f, y2=0.f, y3=0.f;
        int nb = half*8;
        for (int i = 0; i < 8; ++i) {
            int nli = nb + i;
            float L1n = L1l[nli], bbn = bbl[nli];
            float racc = 0.f, q1 = 0.f;
            #pragma unroll
            for (int q = 0; q < DD; ++q) {
                float4 v = *(const float4*)&pkl[nli][q][0];
                float z = zr[q];
                racc = fmaf(v.x, z, racc);
                racc = fmaf(v.y, z*z, racc);
                float t = fmaf(v.z, z, v.w);
                q1 = fmaf(t, z, q1);
            }
            int gn = n0 + nli;
            r_g[gn*MM + m] = L1n + racc - sm;
            float p1 = __expf(fmaf(-0.5f, q1, bbn));
            float4 xo = *(const float4*)(Xm + (LTT+gn)*QQ);
            y0 = fmaf(p1, xo.x, y0); y1 = fmaf(p1, xo.y, y1);
            y2 = fmaf(p1, xo.z, y2); y3 = fmaf(p1, xo.w, y3);
        }
        if (half == 0) {
            yredl[m*4+0]=y0; yredl[m*4+1]=y1; yredl[m*4+2]=y2; yredl[m*4+3]=y3;
        }
        __syncthreads();
        if (half == 1) {
            yredl[m*4+0]+=y0; yredl[m*4+1]+=y1; yredl[m*4+2]+=y2; yredl[m*4+3]+=y3;
        }
        __syncthreads();
        for (int e = tid; e < 512; e += 256) atomicAdd(&Yg[e], yredl[e]);
    } else if (b < 320) {
        int idx = (b-256)*256 + tid;
        int i = idx >> 7, j = idx & 127;
        float var = varp[0];
        float s = 0.f;
        for (int q = 0; q < DD; ++q) {
            float l = ls[q];
            float d = (Zg[i*DD+q] - Zg[j*DD+q]) / l;
            s += d*d;
        }
        float v = var * __expf(-0.5f*s);
        if (i == j) v += JIT;
        Kuu[idx] = v;
    } else {
        for (int e = tid; e < MM*DD; e += 256) Zh[e] = (_Float16)Zg[e];
    }
}

// ============ linalg device functions (LDS stride 132) ============
__device__ __forceinline__ void dev_chol(float* mat, int tid)
{
    int wv = tid >> 6, ln = tid & 63;
    for (int p = 0; p < 8; ++p) {
        int base = p*16;
        if (wv == 0) {
            int r0 = base + ln, r1 = r0 + 64;
            bool h0 = r0 < 128, h1 = r1 < 128;
            float a0[16], a1[16];
            #pragma unroll
            for (int c = 0; c < 16; ++c) {
                a0[c] = h0 ? mat[r0*132 + base + c] : 0.f;
                a1[c] = h1 ? mat[r1*132 + base + c] : 0.f;
            }
            #pragma unroll
            for (int kk = 0; kk < 16; ++kk) {
                float d   = rlane(a0[kk], kk);
                float rdk = rsqrtf(d);
                float sq  = d * rdk;
                a0[kk] = (ln == kk) ? sq : a0[kk] * rdk;
                a1[kk] *= rdk;
                #pragma unroll
                for (int j = kk+1; j < 16; ++j) {
                    float ljv = rlane(a0[kk], j);
                    a0[j] = fmaf(-a0[kk], ljv, a0[j]);
                    a1[j] = fmaf(-a1[kk], ljv, a1[j]);
                }
            }
            #pragma unroll
            for (int c = 0; c < 16; ++c) {
                if (h0) mat[r0*132 + base + c] = a0[c];
                if (h1) mat[r1*132 + base + c] = a1[c];
            }
        }
        __syncthreads();
        int S = 112 - base;
        if (S > 0) {
            int T = S >> 2, nb = base + 16;
            int nT = (T*(T+1)) >> 1;
            for (int t = tid; t < nT; t += 512) {
                int ti = (int)(0.5f*(sqrtf(8.f*(float)t + 1.f) - 1.f));
                if ((ti+1)*(ti+2)/2 <= t) ++ti;
                else if (ti*(ti+1)/2 > t) --ti;
                int tj = t - ((ti*(ti+1))>>1);
                int i0 = nb + ti*4, j0 = nb + tj*4;
                float ac[4][4];
                #pragma unroll
                for (int r = 0; r < 4; ++r)
                    #pragma unroll
                    for (int s = 0; s < 4; ++s) ac[r][s] = mat[(i0+r)*132 + j0 + s];
                #pragma unroll
                for (int c4 = 0; c4 < 4; ++c4) {
                    float4 av[4], bv[4];
                    #pragma unroll
                    for (int r = 0; r < 4; ++r) {
                        av[r] = *(const float4*)&mat[(i0+r)*132 + base + c4*4];
                        bv[r] = *(const float4*)&mat[(j0+r)*132 + base + c4*4];
                    }
                    #pragma unroll
                    for (int r = 0; r < 4; ++r)
                        #pragma unroll
                        for (int s = 0; s < 4; ++s)
                            ac[r][s] -= av[r].x*bv[s].x + av[r].y*bv[s].y
                                      + av[r].z*bv[s].z + av[r].w*bv[s].w;
                }
                #pragma unroll
                for (int r = 0; r < 4; ++r)
                    #pragma unroll
                    for (int s = 0; s < 4; ++s) mat[(i0+r)*132 + j0 + s] = ac[r][s];
            }
        }
        __syncthreads();
    }
}

__device__ __forceinline__ void dev_dinv(const float* mat, float* dinvb, int tid)
{
    int wv = tid >> 6, ln = tid & 63;
    if (ln < 16) {
        int c = ln, bd = wv;
        int base = bd*16;
        float x[16];
        #pragma unroll
        for (int i = 0; i < 16; ++i) {
            float dii = mat[(base+i)*132 + base + i];
            float s = 0.f;
            #pragma unroll
            for (int j = 0; j < i; ++j) s += mat[(base+i)*132 + base + j] * x[j];
            float v;
            if (i < c) v = 0.f;
            else if (i == c) v = 1.0f / dii;
            else v = -s / dii;
            x[i] = v;
        }
        #pragma unroll
        for (int i = 0; i < 16; ++i) dinvb[bd*256 + i*16 + c] = x[i];
    }
    __syncthreads();
}

// ============ K2: block0 = chol(Kuu)+Linv; blocks 1-1152 = psi2 ============
__global__ __launch_bounds__(512) void psi2chol_kernel(
    const _Float16* __restrict__ Zh, const float* __restrict__ r_g,
    const _Float16* __restrict__ bh, float* __restrict__ psi2,
    const float* __restrict__ Kuu, float* __restrict__ Lg,
    float* __restrict__ scalars)
{
    __shared__ float shm[19968];   // 79.9 KB -> 2 blocks/CU
    int tid = threadIdx.x;
    if (blockIdx.x == 0) {
        float* mat   = shm;            // 16896
        float* dinvb = shm + 16896;    // 2048
        float* red   = shm + 18944;    // 512
        float* tmpM  = shm + 19456;    // 512
        for (int e = tid; e < 16384; e += 512) mat[(e>>7)*132 + (e&127)] = Kuu[e];
        __syncthreads();
        dev_chol(mat, tid);
        red[tid] = (tid < 128) ? logf(mat[tid*132 + tid]) : 0.f;
        __syncthreads();
        for (int s = 256; s; s >>= 1) { if (tid < s) red[tid] += red[tid+s]; __syncthreads(); }
        if (tid == 0) scalars[0] = red[0];
        dev_dinv(mat, dinvb, tid);
        // ---- in-place blocked lower-triangular inverse ----
        #pragma unroll
        for (int bi = 1; bi < 8; ++bi) {
            const int total = bi*256;
            const int np = (total + 511)/512;
            float wbuf[4];
            #pragma unroll
            for (int ps = 0; ps < np; ++ps) {
                int e = ps*512 + tid;
                float Mv = 0.f;
                int bj = e >> 8, r = (e >> 4) & 15, c = e & 15;
                if (e < total) {
                    #pragma unroll
                    for (int kk = 0; kk < 16; ++kk)
                        Mv = fmaf(mat[(bi*16+r)*132 + bj*16+kk], dinvb[bj*256 + kk*16 + c], Mv);
                    for (int k = bj+1; k < bi; ++k)
                        #pragma unroll
                        for (int kk = 0; kk < 16; ++kk)
                            Mv = fmaf(mat[(bi*16+r)*132 + k*16+kk], mat[(k*16+kk)*132 + bj*16+c], Mv);
                }
                __syncthreads();
                if (e < total) tmpM[tid] = Mv;
                __syncthreads();
                float w = 0.f;
                if (e < total) {
                    int lbj = tid >> 8;
                    #pragma unroll
                    for (int kk = 0; kk < 16; ++kk)
                        w = fmaf(dinvb[bi*256 + r*16 + kk], tmpM[lbj*256 + kk*16 + c], w);
                }
                wbuf[ps] = w;
            }
            __syncthreads();
            #pragma unroll
            for (int ps = 0; ps < np; ++ps) {
                int e = ps*512 + tid;
                if (e < total) {
                    int bj = e >> 8, r = (e >> 4) & 15, c = e & 15;
                    mat[(bi*16+r)*132 + bj*16 + c] = -wbuf[ps];
                }
            }
            __syncthreads();
        }
        // diagonal blocks = Dinv
        for (int e = tid; e < 2048; e += 512) {
            int bd = e >> 8, r = (e >> 4) & 15, c = e & 15;
            mat[(bd*16+r)*132 + bd*16 + c] = dinvb[e];
        }
        __syncthreads();
        for (int e = tid; e < 16384; e += 512) Lg[e] = mat[(e>>7)*132 + (e&127)];
    } else {
        float (*pacc)[64][4] = (float(*)[64][4])shm;
        int w = tid >> 6, l = tid & 63, lm = l & 15, lg = l >> 4;
        int b = blockIdx.x - 1;
        int t = b % 36, nq = b / 36;
        int kt = (int)(0.5f*(sqrtf(8.f*(float)t + 1.f) - 1.f));
        if ((kt+1)*(kt+2)/2 <= t) ++kt;
        else if (kt*(kt+1)/2 > t) --kt;
        int mt = t - ((kt*(kt+1))>>1);     // mt <= kt

        half8 Bf = ((const half8*)Zh)[(kt*16 + lm)*4 + lg];
        half8 Zm = ((const half8*)Zh)[(mt*16 + lm)*4 + lg];
        f32x4 z4; z4[0]=0.f; z4[1]=0.f; z4[2]=0.f; z4[3]=0.f;
        f32x4 acc0 = z4, acc1 = z4;
        int n0g = nq*128 + w*16;
        const float* rbase = r_g + (size_t)n0g*MM;
        const half8* bbase = (const half8*)bh + (size_t)n0g*4;
        for (int i = 0; i < 16; i += 2) {
            half8 bf0 = bbase[i*4 + lg];
            half8 bf1 = bbase[i*4 + 4 + lg];
            const float* rn0 = rbase + i*MM;
            f32x4 rm0 = *(const f32x4*)(rn0 + mt*16 + lg*4);
            f32x4 rm1 = *(const f32x4*)(rn0 + MM + mt*16 + lg*4);
            float rk0 = rn0[kt*16 + lm];
            float rk1 = rn0[MM + kt*16 + lm];
            half8 A0 = Zm * bf0;
            half8 A1 = Zm * bf1;
            f32x4 p0 = __builtin_amdgcn_mfma_f32_16x16x32_f16(A0, Bf, z4, 0, 0, 0);
            f32x4 p1 = __builtin_amdgcn_mfma_f32_16x16x32_f16(A1, Bf, z4, 0, 0, 0);
            acc0[0] += fexp2(p0[0] + rm0[0] + rk0);
            acc0[1] += fexp2(p0[1] + rm0[1] + rk0);
            acc0[2] += fexp2(p0[2] + rm0[2] + rk0);
            acc0[3] += fexp2(p0[3] + rm0[3] + rk0);
            acc1[0] += fexp2(p1[0] + rm1[0] + rk1);
            acc1[1] += fexp2(p1[1] + rm1[1] + rk1);
            acc1[2] += fexp2(p1[2] + rm1[2] + rk1);
            acc1[3] += fexp2(p1[3] + rm1[3] + rk1);
        }
        #pragma unroll
        for (int j = 0; j < 4; ++j) pacc[w][l][j] = acc0[j] + acc1[j];
        __syncthreads();
        if (tid < 256) {
            int ll = tid >> 2, j = tid & 3;
            float s = 0.f;
            #pragma unroll
            for (int ww = 0; ww < 8; ++ww) s += pacc[ww][ll][j];
            int row = mt*16 + (ll >> 4)*4 + j;
            int col = kt*16 + (ll & 15);
            atomicAdd(&psi2[row*MM + col], s);
            if (mt != kt) atomicAdd(&psi2[col*MM + row], s);
        }
    }
}

// ============ K3: block0 = chol(G)+Y-solve; blocks 1-8 = trace quad-forms; elect final ============
__global__ __launch_bounds__(512) void cholG_kernel(
    const float* __restrict__ Kuu, const float* __restrict__ psi2,
    const float* __restrict__ Yg, const float* __restrict__ Lg,
    const float* __restrict__ varp,
    float* __restrict__ scalars, int* __restrict__ cnt, float* __restrict__ out)
{
    __shared__ float shm[20480];   // 80 KB
    int tid = threadIdx.x;
    if (blockIdx.x == 0) {
        float* mat   = shm;            // 16896
        float* dinvb = shm + 16896;    // 2048
        float* rhs   = shm + 18944;    // 512
        float* red   = shm + 19456;    // 512
        for (int e = tid; e < 16384; e += 512)
            mat[(e>>7)*132 + (e&127)] = Kuu[e] + (1.0f/SIG2)*psi2[e];
        __syncthreads();
        dev_chol(mat, tid);
        red[tid] = (tid < 128) ? logf(mat[tid*132 + tid]) : 0.f;
        __syncthreads();
        for (int s = 256; s; s >>= 1) { if (tid < s) red[tid] += red[tid+s]; __syncthreads(); }
        if (tid == 0) scalars[1] = red[0];
        dev_dinv(mat, dinvb, tid);
        rhs[tid] = Yg[tid];
        __syncthreads();
        // wave-local forward solve, 4 RHS
        if (tid < 64) {
            int r = tid >> 2, cc = tid & 3;
            for (int bi = 0; bi < 8; ++bi) {
                float a0 = rhs[(bi*16+r)*4 + cc], a1 = 0.f, a2 = 0.f, a3 = 0.f;
                for (int bk = 0; bk < bi; ++bk) {
                    const float* mrow = &mat[(bi*16+r)*132 + bk*16];
                    const float* rb   = &rhs[bk*64 + cc];
                    #pragma unroll
                    for (int kk = 0; kk < 16; kk += 4) {
                        a0 = fmaf(-mrow[kk+0], rb[(kk+0)*4], a0);
                        a1 = fmaf(-mrow[kk+1], rb[(kk+1)*4], a1);
                        a2 = fmaf(-mrow[kk+2], rb[(kk+2)*4], a2);
                        a3 = fmaf(-mrow[kk+3], rb[(kk+3)*4], a3);
                    }
                }
                float acc = (a0+a1)+(a2+a3);
                float w = 0.f;
                #pragma unroll
                for (int kk = 0; kk < 16; ++kk)
                    w += dinvb[bi*256 + r*16 + kk] * __shfl(acc, kk*4 + cc, 64);
                rhs[(bi*16+r)*4 + cc] = w;
            }
        }
        __syncthreads();
        { float v = rhs[tid]; red[tid] = v*v; }
        __syncthreads();
        for (int s = 256; s; s >>= 1) { if (tid < s) red[tid] += red[tid+s]; __syncthreads(); }
        if (tid == 0) scalars[2] = red[0];
    } else {
        float* psl  = shm;             // 128*129 = 16512
        float* lrow = shm + 16512;     // 8*130
        float* redl = shm + 17552;     // 512
        for (int e = tid; e < 16384; e += 512)
            psl[(e>>7)*129 + (e&127)] = psi2[e];
        __syncthreads();
        int w = tid >> 6, l = tid & 63;
        float kacc = 0.f;
        for (int kk2 = 0; kk2 < 2; ++kk2) {
            int k = (blockIdx.x - 1)*16 + w*2 + kk2;
            lrow[w*130 + l]      = (l      <= k) ? Lg[k*MM + l]      : 0.f;
            lrow[w*130 + l + 64] = (l + 64 <= k) ? Lg[k*MM + l + 64] : 0.f;
            __syncthreads();
            float wa = 0.f, wb = 0.f;
            for (int j = 0; j <= k; ++j) {
                float lj = lrow[w*130 + j];
                wa = fmaf(psl[j*129 + l],      lj, wa);
                wb = fmaf(psl[j*129 + l + 64], lj, wb);
            }
            float part = wa * lrow[w*130 + l] + wb * lrow[w*130 + l + 64];
            for (int off = 32; off; off >>= 1) part += __shfl_xor(part, off, 64);
            kacc += part;
            __syncthreads();
        }
        if (l == 0) redl[w] = kacc;
        __syncthreads();
        if (tid == 0) {
            float s = 0.f;
            for (int ww = 0; ww < 8; ++ww) s += redl[ww];
            atomicAdd(&scalars[3], s);
        }
    }
    if (tid == 0) {
        __threadfence();
        int old = atomicAdd(cnt, 1);
        if (old == 8) {
            float ldK  = scalars[0];
            float ldG  = atomicAdd(&scalars[1], 0.0f);
            float c2s  = atomicAdd(&scalars[2], 0.0f);
            float trr  = atomicAdd(&scalars[3], 0.0f);
            float s1   = atomicAdd(&scalars[4], 0.0f);
            float s2   = atomicAdd(&scalars[5], 0.0f);
            float s3   = atomicAdd(&scalars[6], 0.0f);
            float var = varp[0];
            float trAAT   = trr / SIG2;
            float logdetB = 2.0f * (ldG - ldK);
            float sumc2   = c2s / (SIG2*SIG2);
            float psi0    = (float)NN * var;
            const float LOG2PI = 1.837877066409345f;
            float NQf = (float)NQ;
            float bound = -0.5f*NQf*(LOG2PI + logf(SIG2));
            bound += -0.5f/SIG2 * s1;
            bound += -0.5f*(float)QQ*(psi0/SIG2 - trAAT);
            bound += -0.5f*(float)QQ*logdetB;
            bound += 0.5f*sumc2;
            bound += 0.5f*s2 + 0.5f*NQf*LOG2PI;
            bound += -(float)(LTT*QQ)*LOG2PI - 0.5f*s3;
            out[0] = bound;
        }
    }
}

extern "C" void kernel_launch(void* const* d_in, const int* in_sizes, int n_in,
                              void* d_out, int out_size, void* d_ws, size_t ws_size,
                              hipStream_t stream)
{
    (void)in_sizes; (void)n_in; (void)out_size; (void)ws_size;
    const float* Xm   = (const float*)d_in[0];
    const float* Xv   = (const float*)d_in[1];
    const float* Zg   = (const float*)d_in[2];
    const float* ls   = (const float*)d_in[3];
    const float* varp = (const float*)d_in[4];

    float* p = (float*)d_ws;
    float*    r_g   = p;                p += NN*MM;
    _Float16* bh    = (_Float16*)p;     p += NN*DD/2;
    _Float16* Zh    = (_Float16*)p;     p += MM*DD/2;
    float*    Kuu   = p;                p += MM*MM;
    float*    Lg    = p;                p += MM*MM;
    // --- contiguous zero-init region ---
    float*    psi2  = p;                p += MM*MM;
    float*    Yg    = p;                p += 512;
    float*    scalars = p;              p += 8;
    int*      cnt   = (int*)p;          p += 4;

    hipMemsetAsync(psi2, 0, (MM*MM + 512 + 8 + 4)*sizeof(float), stream);
    k1_kernel<<<321, 256, 0, stream>>>(Xm, Xv, Zg, ls, varp, bh, r_g, Yg, Zh, Kuu, scalars);
    psi2chol_kernel<<<1153, 512, 0, stream>>>(Zh, r_g, bh, psi2, Kuu, Lg, scalars);
    cholG_kernel<<<9, 512, 0, stream>>>(Kuu, psi2, Yg, Lg, varp, scalars, cnt, (float*)d_out);
}